// Round 4
// baseline (133.027 us; speedup 1.0000x reference)
//
#include <hip/hip_runtime.h>
#include <math.h>

#define SS 8
#define NN 4096
#define MM 64
#define LBOX 20.0f

typedef __attribute__((ext_vector_type(8)))  short    short8;
typedef __attribute__((ext_vector_type(2)))  float    floatx2;
typedef __attribute__((ext_vector_type(4)))  float    floatx4;
typedef __attribute__((ext_vector_type(16))) float    floatx16;
typedef __attribute__((ext_vector_type(2)))  unsigned uintx2;
typedef __attribute__((ext_vector_type(2)))  __bf16   bf16x2;

__device__ inline unsigned pkbf(float a, float b) {   // v_cvt_pk_bf16_f32 (RNE)
    bf16x2 p; p.x = (__bf16)a; p.y = (__bf16)b;
    unsigned u; __builtin_memcpy(&u, &p, 4); return u;
}
__device__ inline unsigned short bfbits(float x) {
    __bf16 b = (__bf16)x;
    unsigned short u; __builtin_memcpy(&u, &b, 2); return u;
}

// One wave per atom (lane = neighbor). All LDS staging is wave-private ->
// no __syncthreads after the weight-staging barrier; s_waitcnt lgkmcnt(0)
// orders wave-internal LDS write->read.
// h2 = relu(h1@W2 + b2) via 2x mfma_32x32x16_bf16 (K row 8 = ones -> bias).
// P[16][4] = H2^T R, q = 1^T R via mfma_16x16x32_bf16 (round-2 verified).
// A[32][4] = en3^T P + b3 (x) q ; D[32][16] = A A[:16]^T (fp32, v_pk_fma).
__global__ __launch_bounds__(256) void desc_kernel(
    const float* __restrict__ pos,      // [S*N*3]
    const int*   __restrict__ types,    // [S*N]
    const int*   __restrict__ neigh,    // [S*N*M]
    const float* __restrict__ es1_w, const float* __restrict__ es1_b,
    const float* __restrict__ es2_w, const float* __restrict__ es2_b,
    const float* __restrict__ fs1_w, const float* __restrict__ fs1_b,
    const float* __restrict__ fs2_w, const float* __restrict__ fs2_b,
    const float* __restrict__ en1_w, const float* __restrict__ en1_b,
    const float* __restrict__ en2_w, const float* __restrict__ en2_b,
    const float* __restrict__ en3_w, const float* __restrict__ en3_b,
    float* __restrict__ out)            // [S*N*32*16]
{
    __shared__ alignas(16) unsigned short sh_W2x[2][16][8]; // bf16 B-frags: [0][c][j]=W2[j][c]; [1][c][j]= j? 0 : b2[c]
    __shared__ alignas(16) unsigned short sh_h2[4][16][72]; // bf16 [wave][h][m]
    __shared__ alignas(16) unsigned short sh_rt[4][4][72];  // bf16 [wave][d][m]
    __shared__ alignas(16) float sh_PT[4][4][20];           // fp32 P^T [wave][d][h]
    __shared__ alignas(16) float sh_W3p[512];               // paired en3: [h/2][g][4]={W3[2h][g],W3[2h][g+16],W3[2h+1][g],W3[2h+1][g+16]}
    __shared__ alignas(16) float sh_b3p[16][2];             // {b3[g], b3[g+16]}
    __shared__ alignas(16) float sh_A[4][128];              // A[g][d] flat g*4+d
    __shared__ alignas(16) float sh_vt[4][8];               // td[pair] @ en1_w

    const int tid = threadIdx.x;

    // ---------------- per-block weight staging (only block-wide sync point) ----------------
    if (tid < 4) {  // species-pair table -> vt = td @ en1_w
        const float ti = (float)(tid >> 1), tj = (float)(tid & 1);
        float e[4] = {0.f, 0.f, 0.f, 0.f};
        #pragma unroll
        for (int swp = 0; swp < 2; ++swp) {
            const float a = swp ? tj : ti, b = swp ? ti : tj;
            float h[4];
            #pragma unroll
            for (int k = 0; k < 4; ++k)
                h[k] = fmaxf(a * es1_w[k] + b * es1_w[4 + k] + es1_b[k], 0.f);
            #pragma unroll
            for (int k = 0; k < 4; ++k) {
                float acc = es2_b[k];
                #pragma unroll
                for (int j = 0; j < 4; ++j) acc += h[j] * es2_w[j * 4 + k];
                e[k] += acc;
            }
        }
        float f[4];
        #pragma unroll
        for (int k = 0; k < 4; ++k) {
            float acc = fs1_b[k];
            #pragma unroll
            for (int j = 0; j < 4; ++j) acc += e[j] * fs1_w[j * 4 + k];
            f[k] = fmaxf(acc, 0.f);
        }
        float td[4];
        #pragma unroll
        for (int k = 0; k < 4; ++k) {
            float acc = fs2_b[k];
            #pragma unroll
            for (int j = 0; j < 4; ++j) acc += f[j] * fs2_w[j * 4 + k];
            td[k] = acc;
        }
        #pragma unroll
        for (int o = 0; o < 8; ++o) {
            float acc = 0.f;
            #pragma unroll
            for (int d = 0; d < 4; ++d) acc += td[d] * en1_w[d * 8 + o];
            sh_vt[tid][o] = acc;
        }
    }
    {   // W2 B-frags (bf16), bias folded as extra K row
        const int q = tid >> 7, col = (tid >> 3) & 15, j = tid & 7;
        const float wv = q ? (j == 0 ? en2_b[col] : 0.f) : en2_w[j * 16 + col];
        sh_W2x[q][col][j] = bfbits(wv);
    }
    #pragma unroll
    for (int rr = 0; rr < 2; ++rr) {   // en3 paired for v_pk_fma A-step
        const int i = tid + rr * 256;
        const int hp = i >> 6, g = (i >> 2) & 15, w = i & 3;
        sh_W3p[i] = en3_w[(2 * hp + (w >> 1)) * 32 + g + 16 * (w & 1)];
    }
    if (tid < 32) sh_b3p[tid >> 1][tid & 1] = en3_b[(tid & 1) * 16 + (tid >> 1)];
    __syncthreads();

    const int wave = __builtin_amdgcn_readfirstlane(tid >> 6);
    const int lane = tid & 63;
    const int atom = __builtin_amdgcn_readfirstlane(blockIdx.x * 4 + (tid >> 6)); // s*N + n
    const int sbase = atom & ~(NN - 1);

    // ---------------- per-neighbor geometry (atom-uniform values scalarized) ----------------
    const float xi = pos[atom * 3 + 0];
    const float yi = pos[atom * 3 + 1];
    const float zi = pos[atom * 3 + 2];
    const int   ti = types[atom];

    const int nb  = neigh[atom * MM + lane];
    const int msk = nb < 0;
    const int gj  = sbase + (msk ? 0 : nb);

    const float* pj = pos + gj * 3;
    float dx = pj[0] - xi;
    float dy = pj[1] - yi;
    float dz = pj[2] - zi;
    dx -= LBOX * rintf(dx * (1.0f / LBOX));
    dy -= LBOX * rintf(dy * (1.0f / LBOX));
    dz -= LBOX * rintf(dz * (1.0f / LBOX));
    const float r2   = fmaf(dx, dx, fmaf(dy, dy, fmaf(dz, dz, 1e-12f)));
    const float rinv = rsqrtf(r2);
    const float r    = r2 * rinv;
    const float u    = fminf(fmaxf((r - 2.0f) * 0.25f, 0.0f), 1.0f);  // clamp: exact at both ends
    const float swv  = 0.5f * __cosf(3.14159265358979323846f * u) + 0.5f;
    const float sij   = msk ? 0.0f : swv * rinv;
    const float scale = sij * rinv;

    const int tj = types[gj];
    const int tt = ti * 2 + tj;

    // ---------------- h1 = relu(sij*vt[tt] + b1), packed bf16 ----------------
    unsigned hp[4];
    {
        const float4 va = *(const float4*)(&sh_vt[tt][0]);
        const float4 vb = *(const float4*)(&sh_vt[tt][4]);
        const float h0 = fmaxf(fmaf(sij, va.x, en1_b[0]), 0.f);
        const float h1v= fmaxf(fmaf(sij, va.y, en1_b[1]), 0.f);
        const float h2v= fmaxf(fmaf(sij, va.z, en1_b[2]), 0.f);
        const float h3 = fmaxf(fmaf(sij, va.w, en1_b[3]), 0.f);
        const float h4 = fmaxf(fmaf(sij, vb.x, en1_b[4]), 0.f);
        const float h5 = fmaxf(fmaf(sij, vb.y, en1_b[5]), 0.f);
        const float h6 = fmaxf(fmaf(sij, vb.z, en1_b[6]), 0.f);
        const float h7 = fmaxf(fmaf(sij, vb.w, en1_b[7]), 0.f);
        hp[0] = pkbf(h0, h1v); hp[1] = pkbf(h2v, h3);
        hp[2] = pkbf(h4, h5);  hp[3] = pkbf(h6, h7);
    }

    // ---------------- h2 on the matrix pipe: 2x mfma_32x32x16 ----------------
    const int q2 = lane >> 5;
    union U { unsigned u[4]; short8 v; } a0, a1;
    #pragma unroll
    for (int i = 0; i < 4; ++i) {
        const unsigned other = (unsigned)__shfl_xor((int)hp[i], 32, 64);
        const unsigned bias  = (i == 0) ? 0x3F80u : 0u;   // bf16 1.0 -> k=8 row folds en2_b
        a0.u[i] = q2 ? bias : hp[i];
        a1.u[i] = q2 ? bias : other;
    }
    const short8 bw = *(const short8*)&sh_W2x[q2][lane & 15][0];
    floatx16 c0 = {}, c1 = {};
    c0 = __builtin_amdgcn_mfma_f32_32x32x16_bf16(a0.v, bw, c0, 0, 0, 0);
    c1 = __builtin_amdgcn_mfma_f32_32x32x16_bf16(a1.v, bw, c1, 0, 0, 0);

    // epilogue: relu + bf16, vectorized b64 writes to [h][m] layout
    const int col32 = lane & 31;
    if (col32 < 16) {
        unsigned short* row = &sh_h2[wave][col32][0];
        #pragma unroll
        for (int g = 0; g < 4; ++g) {
            const int m = 8 * g + 4 * q2;
            uintx2 w0, w1;
            w0.x = pkbf(fmaxf(c0[4*g+0], 0.f), fmaxf(c0[4*g+1], 0.f));
            w0.y = pkbf(fmaxf(c0[4*g+2], 0.f), fmaxf(c0[4*g+3], 0.f));
            *(uintx2*)(row + m) = w0;
            w1.x = pkbf(fmaxf(c1[4*g+0], 0.f), fmaxf(c1[4*g+1], 0.f));
            w1.y = pkbf(fmaxf(c1[4*g+2], 0.f), fmaxf(c1[4*g+3], 0.f));
            *(uintx2*)(row + 32 + m) = w1;
        }
    }
    {
        const unsigned p0 = pkbf(sij, dx * scale), p1 = pkbf(dy * scale, dz * scale);
        sh_rt[wave][0][lane] = (unsigned short)p0;
        sh_rt[wave][1][lane] = (unsigned short)(p0 >> 16);
        sh_rt[wave][2][lane] = (unsigned short)p1;
        sh_rt[wave][3][lane] = (unsigned short)(p1 >> 16);
    }
    asm volatile("s_waitcnt lgkmcnt(0)" ::: "memory");

    // ---------------- P = H2^T R and q = 1^T R (matrix pipe) ----------------
    const int col16 = lane & 15;
    const int q4    = lane >> 4;
    const int m0    = q4 * 8;
    floatx4 cP = {0.f, 0.f, 0.f, 0.f};
    floatx4 cQ = {0.f, 0.f, 0.f, 0.f};
    const short8 ones = (short8)(short)0x3F80;
    #pragma unroll
    for (int ck = 0; ck < 2; ++ck) {
        const short8 af = *(const short8*)&sh_h2[wave][col16][ck * 32 + m0];
        const short8 bf = *(const short8*)&sh_rt[wave][col16 & 3][ck * 32 + m0];
        cP = __builtin_amdgcn_mfma_f32_16x16x32_bf16(af, bf, cP, 0, 0, 0);
        cQ = __builtin_amdgcn_mfma_f32_16x16x32_bf16(ones, bf, cQ, 0, 0, 0);
    }
    if (col16 < 4) *(floatx4*)&sh_PT[wave][col16][q4 * 4] = cP;
    const float qd = cQ[0];                    // q[lane&3]
    asm volatile("s_waitcnt lgkmcnt(0)" ::: "memory");

    // ---------------- A[g][d] = en3^T P + b3 q  (v_pk_fma pairs g,g+16) ----------------
    {
        const int g0 = lane >> 2, dd = lane & 3;
        const floatx2 b3v = *(const floatx2*)&sh_b3p[g0][0];
        floatx2 acc2 = floatx2{qd, qd} * b3v;
        #pragma unroll
        for (int h4 = 0; h4 < 4; ++h4) {
            const floatx4 pv = *(const floatx4*)&sh_PT[wave][dd][h4 * 4];
            const floatx4 wa = *(const floatx4*)&sh_W3p[(h4 * 2 + 0) * 64 + g0 * 4];
            const floatx4 wb = *(const floatx4*)&sh_W3p[(h4 * 2 + 1) * 64 + g0 * 4];
            acc2 += floatx2{pv.x, pv.x} * floatx2{wa.x, wa.y};
            acc2 += floatx2{pv.y, pv.y} * floatx2{wa.z, wa.w};
            acc2 += floatx2{pv.z, pv.z} * floatx2{wb.x, wb.y};
            acc2 += floatx2{pv.w, pv.w} * floatx2{wb.z, wb.w};
        }
        sh_A[wave][lane]      = acc2.x;   // lane == g0*4+dd
        sh_A[wave][lane + 64] = acc2.y;
    }
    asm volatile("s_waitcnt lgkmcnt(0)" ::: "memory");

    // ---------------- D[g][k] = A A[:16]^T ; coalesced nt store ----------------
    {
        const int g = lane >> 1, koff = (lane & 1) * 8;
        const floatx4 Ag = *(const floatx4*)&sh_A[wave][g * 4];
        floatx4 o0, o1;
        #pragma unroll
        for (int jj = 0; jj < 8; ++jj) {
            const floatx4 Ak = *(const floatx4*)&sh_A[wave][(koff + jj) * 4];
            const float v = fmaf(Ag.x, Ak.x, fmaf(Ag.y, Ak.y, fmaf(Ag.z, Ak.z, Ag.w * Ak.w)));
            if (jj < 4) o0[jj] = v; else o1[jj - 4] = v;
        }
        float* op = out + (size_t)atom * 512 + lane * 8;
        __builtin_nontemporal_store(o0, (floatx4*)op);
        __builtin_nontemporal_store(o1, (floatx4*)(op + 4));
    }
}

extern "C" void kernel_launch(void* const* d_in, const int* in_sizes, int n_in,
                              void* d_out, int out_size, void* d_ws, size_t ws_size,
                              hipStream_t stream) {
    const float* pos   = (const float*)d_in[0];
    const int*   typ   = (const int*)d_in[1];
    const int*   ngh   = (const int*)d_in[2];
    desc_kernel<<<dim3((SS * NN) / 4), dim3(256), 0, stream>>>(
        pos, typ, ngh,
        (const float*)d_in[3],  (const float*)d_in[4],
        (const float*)d_in[5],  (const float*)d_in[6],
        (const float*)d_in[7],  (const float*)d_in[8],
        (const float*)d_in[9],  (const float*)d_in[10],
        (const float*)d_in[11], (const float*)d_in[12],
        (const float*)d_in[13], (const float*)d_in[14],
        (const float*)d_in[15], (const float*)d_in[16],
        (float*)d_out);
}